// Round 1
// baseline (130.020 us; speedup 1.0000x reference)
//
#include <hip/hip_runtime.h>

// Problem: B=8, C=32, H=W=64, OUT=32, KBITS=8, 3x3 grouped conv per (bit, channel),
// per-(k,c,o) fake-quant (round(12.5*y)/12.5) BEFORE the c-sum, then coef[k] combine.
// out[b,o,h,w] = sum_{c,k} (coef[k]/12.5) * rint( sum_j (12.5*w[k,c,o,j])*x_j + 12.5*b[k,c,o] )

#define NB    8     // weight bits
#define NC    32    // input channels
#define NO    32    // out channels per group
#define NH    64
#define NW    64
#define NBATCH 8

// Repack + pre-scale weights: wq[((c*32+o)*8 + k)*10 + j] = 12.5*w[k][c*32+o][j] (j<9), j==9 -> 12.5*bias
__global__ void prep_wq(const float* __restrict__ w, const float* __restrict__ bias,
                        float* __restrict__ wq) {
    int idx = blockIdx.x * 256 + threadIdx.x;        // idx = (c*32+o)*8 + k
    if (idx >= NC * NO * NB) return;
    int k  = idx & 7;
    int ch = idx >> 3;                               // c*32+o
    const float* ws = w + ((size_t)k * (NC * NO) + ch) * 9;
    float* dst = wq + (size_t)idx * 10;
#pragma unroll
    for (int j = 0; j < 9; ++j) dst[j] = 12.5f * ws[j];
    dst[9] = 12.5f * bias[k * (NC * NO) + ch];
}

// One wave (64 lanes) = one (b, h, o-group-of-4). lane = w column.
__global__ __launch_bounds__(256) void demolition_conv(
        const float* __restrict__ x, const float* __restrict__ wq,
        float* __restrict__ out) {
    const int w    = threadIdx.x & 63;
    const int wave = __builtin_amdgcn_readfirstlane((int)(threadIdx.x >> 6));
    const int og   = blockIdx.x * 4 + wave;          // 0..7, wave-uniform
    const int h    = blockIdx.y;
    const int b    = blockIdx.z;
    const int o0   = og * 4;

    // coef[k]/12.5
    const float ckq[8] = {
        -128.f / 127.f / 12.5f,  1.f / 127.f / 12.5f,  2.f / 127.f / 12.5f,
           4.f / 127.f / 12.5f,  8.f / 127.f / 12.5f, 16.f / 127.f / 12.5f,
          32.f / 127.f / 12.5f, 64.f / 127.f / 12.5f };

    float acc0 = 0.f, acc1 = 0.f, acc2 = 0.f, acc3 = 0.f;

    const float* xb = x + ((size_t)b * NC * NH + h) * NW + w;   // c=0 plane, row h, col w
    const bool rm = (h > 0);        // row h-1 valid (wave-uniform)
    const bool rp = (h < NH - 1);   // row h+1 valid

    for (int c = 0; c < NC; ++c) {
        const float* xp = xb + (size_t)c * (NH * NW);
        float xr[9];
        // center row (always valid)
        xr[4] = xp[0];
        xr[3] = (w > 0)      ? xp[-1] : 0.f;
        xr[5] = (w < NW - 1) ? xp[1]  : 0.f;
        if (rm) {
            const float* r = xp - NW;
            xr[1] = r[0];
            xr[0] = (w > 0)      ? r[-1] : 0.f;
            xr[2] = (w < NW - 1) ? r[1]  : 0.f;
        } else { xr[0] = xr[1] = xr[2] = 0.f; }
        if (rp) {
            const float* r = xp + NW;
            xr[7] = r[0];
            xr[6] = (w > 0)      ? r[-1] : 0.f;
            xr[8] = (w < NW - 1) ? r[1]  : 0.f;
        } else { xr[6] = xr[7] = xr[8] = 0.f; }

        // wave-uniform weight base for this (c, o0)
        const int wbase = __builtin_amdgcn_readfirstlane((c * NO + o0) * NB * 10);
        const float* __restrict__ wp = wq + wbase;

        for (int oi = 0; oi < 4; ++oi) {
            const float* __restrict__ wo = wp + oi * (NB * 10);
            float a = (oi == 0) ? acc0 : (oi == 1) ? acc1 : (oi == 2) ? acc2 : acc3;
#pragma unroll
            for (int k = 0; k < NB; ++k) {
                const float* __restrict__ f = wo + k * 10;
                float s = f[9];                       // pre-scaled bias
#pragma unroll
                for (int j = 0; j < 9; ++j) s = fmaf(f[j], xr[j], s);
                a = fmaf(ckq[k], rintf(s), a);
            }
            if (oi == 0) acc0 = a; else if (oi == 1) acc1 = a;
            else if (oi == 2) acc2 = a; else acc3 = a;
        }
    }

    float* op = out + (((size_t)b * NO + o0) * NH + h) * NW + w;
    op[0 * NH * NW] = acc0;
    op[1 * NH * NW] = acc1;
    op[2 * NH * NW] = acc2;
    op[3 * NH * NW] = acc3;
}

extern "C" void kernel_launch(void* const* d_in, const int* in_sizes, int n_in,
                              void* d_out, int out_size, void* d_ws, size_t ws_size,
                              hipStream_t stream) {
    const float* x    = (const float*)d_in[0];   // [8,32,64,64]
    const float* wt   = (const float*)d_in[1];   // [8,1024,1,3,3]
    const float* bias = (const float*)d_in[2];   // [8,1024]
    float* out = (float*)d_out;                  // [8,32,64,64]
    float* wq  = (float*)d_ws;                   // 8192*10 floats = 320 KiB

    prep_wq<<<(NC * NO * NB + 255) / 256, 256, 0, stream>>>(wt, bias, wq);

    dim3 grid(2, NH, NBATCH);                    // og-halves, h, b
    demolition_conv<<<grid, 256, 0, stream>>>(x, wq, out);
}